// Round 8
// baseline (481.052 us; speedup 1.0000x reference)
//
#include <hip/hip_runtime.h>

typedef short short8 __attribute__((ext_vector_type(8)));
typedef float floatx4 __attribute__((ext_vector_type(4)));
typedef unsigned short u16;
typedef unsigned int u32;

__device__ __forceinline__ float bits2f(u16 u) {
  union { unsigned int i; float f; } w;
  w.i = ((unsigned int)u) << 16;
  return w.f;
}

__device__ __forceinline__ u16 f2bf(float f) {
  union { float f; unsigned int i; } w;
  w.f = f;
  unsigned int x = w.i;
  unsigned int r = (x + 0x7FFFu + ((x >> 16) & 1u)) >> 16;  // RNE
  return (u16)r;
}

// tanh-form GELU via sigmoid; max abs dev from exact ~3e-4
__device__ __forceinline__ float gelu_f(float x) {
  float t = x * (1.5957691216057308f + 0.07135481283247914f * x * x);
  return x / (1.0f + __expf(-t));
}

// async global->LDS, 16 B per lane; lds dest = wave-uniform base + lane*16
__device__ __forceinline__ void g2l16(const u16* g, u16* l) {
  __builtin_amdgcn_global_load_lds(
      (const __attribute__((address_space(1))) u32*)(const void*)g,
      (__attribute__((address_space(3))) u32*)(void*)l, 16, 0, 0);
}

// ------------- fused prep: cvt x->bf16, pack qkv bias, 5 weight transposes ---
__global__ __launch_bounds__(256) void prep_kernel(
    const float* __restrict__ x, u16* __restrict__ xb,
    const float* __restrict__ bq, const float* __restrict__ bk,
    const float* __restrict__ bv, float* __restrict__ biasqkv,
    const float* __restrict__ Wq, const float* __restrict__ Wk,
    const float* __restrict__ Wv, const float* __restrict__ Wo,
    const float* __restrict__ W1,
    u16* __restrict__ WTqkv, u16* __restrict__ WTo, u16* __restrict__ WT1) {
  __shared__ float tile[32][33];
  int bid = blockIdx.x;
  int tid = threadIdx.x;
  if (bid < 3072) {  // cvt: 3072*256*8 == 16*512*768
    int i = bid * 256 + tid;
    const float4* p = (const float4*)x + (size_t)i * 2;
    float4 a = p[0], b = p[1];
    u16 t[8] = {f2bf(a.x), f2bf(a.y), f2bf(a.z), f2bf(a.w),
                f2bf(b.x), f2bf(b.y), f2bf(b.z), f2bf(b.w)};
    *(int4*)(xb + (size_t)i * 8) = *(const int4*)t;
    return;
  }
  if (bid < 3081) {  // bias pack
    int i = (bid - 3072) * 256 + tid;
    biasqkv[i] = (i < 768) ? bq[i] : (i < 1536 ? bk[i - 768] : bv[i - 1536]);
    return;
  }
  const float* W;
  u16* WT;
  int K, N, bx, by;
  if (bid < 5385) {  // 4 square transposes, 576 blocks each
    int s = bid - 3081;
    int wsel = s / 576;
    int r = s - wsel * 576;
    K = 768; N = 768; bx = r % 24; by = r / 24;
    if (wsel == 0)      { W = Wq; WT = WTqkv; }
    else if (wsel == 1) { W = Wk; WT = WTqkv + 768 * 768; }
    else if (wsel == 2) { W = Wv; WT = WTqkv + 2 * 768 * 768; }
    else                { W = Wo; WT = WTo; }
  } else {  // W1 [768,3072] -> WT1 [3072,768]
    int r = bid - 5385;
    K = 768; N = 3072; bx = r % 96; by = r / 96;
    W = W1; WT = WT1;
  }
  int tx = tid & 31, ty = tid >> 5;
  int n0 = bx * 32, k0 = by * 32;
#pragma unroll
  for (int i = 0; i < 4; i++)
    tile[ty + i * 8][tx] = W[(size_t)(k0 + ty + i * 8) * N + n0 + tx];
  __syncthreads();
#pragma unroll
  for (int i = 0; i < 4; i++)
    WT[(size_t)(n0 + ty + i * 8) * K + k0 + tx] = f2bf(tile[tx][ty + i * 8]);
}

// ------------- standalone transpose (for W2; WT2 aliases WTqkv) --------------
__global__ __launch_bounds__(256) void transpose_k(const float* __restrict__ W,
                                                   u16* __restrict__ WT,
                                                   int K, int N) {
  __shared__ float tile[32][33];
  int tx = threadIdx.x & 31;
  int ty = threadIdx.x >> 5;
  int n0 = blockIdx.x * 32;
  int k0 = blockIdx.y * 32;
#pragma unroll
  for (int i = 0; i < 4; i++)
    tile[ty + i * 8][tx] = W[(size_t)(k0 + ty + i * 8) * N + n0 + tx];
  __syncthreads();
#pragma unroll
  for (int i = 0; i < 4; i++)
    WT[(size_t)(n0 + ty + i * 8) * K + k0 + tx] = f2bf(tile[tx][ty + i * 8]);
}

// ------------- dbuf GEMM, fragment-major LDS: C = A(lda) @ BT^T + bias -------
// BM=128, BK=32, 256 threads, double-buffered, one __syncthreads per K-iter.
// LDS tile layout = fragment-major: per 16-row group, [quad][l15][8 elems] —
// exactly the MFMA A/B fragment order. Staging: wave w, lane l stages row
// 16w+(l&15), k-octet (l>>4); DMA's forced base+lane*16 order then equals the
// fragment order, and fragment ds_read_b128 is lane-sequential (conflict-free;
// old [row][32] layout had lanes on banks {0,16} -> ~8-way conflict).
// XCD swizzle requires gridDim.y==64, gridDim.x%6==0.
template <int BN>
__global__ __launch_bounds__(256) void gemm_m97(
    const u16* __restrict__ A, int lda, const u16* __restrict__ BT,
    const float* __restrict__ bias, void* __restrict__ Cv,
    int M, int N, int K, int act, int c_fp32) {
  constexpr int BM = 128, BK = 32;
  constexpr int ASZ = BM * BK, BSZ = BN * BK;
  __shared__ __align__(16) u16 As[2 * ASZ];
  __shared__ __align__(16) u16 Bs[2 * BSZ];
  int tid = threadIdx.x;
  int wave = tid >> 6;
  int lane = tid & 63;
  int l15 = lane & 15;
  int quad = lane >> 4;

  // XCD-aware swizzle: lin%8 -> XCD band of 8 m-blocks; 8m x 6n supertiles
  int nb = gridDim.x;
  int lin = blockIdx.y * nb + blockIdx.x;
  int xcd = lin & 7;
  int i = lin >> 3;
  int grp = i / 48;
  int rem = i - grp * 48;
  int nblk = grp * 6 + (rem % 6);
  int mblk = (xcd << 3) + rem / 6;
  int m0 = mblk * BM;
  int n0 = nblk * BN;

  constexpr int MT = (BN == 128) ? 4 : 2;
  constexpr int NT = 4;
  int wm = (BN == 128) ? (wave & 1) * 64 : wave * 32;
  int wn = (BN == 128) ? (wave >> 1) * 64 : 0;

  floatx4 acc[MT][NT];
#pragma unroll
  for (int mi = 0; mi < MT; mi++)
#pragma unroll
    for (int ni = 0; ni < NT; ni++) acc[mi][ni] = (floatx4){0.f, 0.f, 0.f, 0.f};

  // staging source: wave w, lane l -> row 16w+(l&15), k-cols (l>>4)*8..+8
  int sr = 16 * wave + l15;   // row within 64-row chunk
  int sc = quad * 8;          // k-octet
  const u16* Ag0 = A + (size_t)(m0 + sr) * lda + sc;
  const u16* Ag1 = A + (size_t)(m0 + 64 + sr) * lda + sc;
  const u16* Bg0 = BT + (size_t)(n0 + sr) * K + sc;
  const u16* Bg1 = BT + (size_t)(n0 + 64 + sr) * K + sc;  // BN==128 only
  int woff = wave * 512;      // wave-uniform LDS base (elems)

  auto stage = [&](int k0, int buf) {
    u16* Ab = As + buf * ASZ;
    u16* Bb = Bs + buf * BSZ;
    g2l16(Ag0 + k0, Ab + woff);
    g2l16(Ag1 + k0, Ab + 2048 + woff);
    g2l16(Bg0 + k0, Bb + woff);
    if constexpr (BN == 128) g2l16(Bg1 + k0, Bb + 2048 + woff);
  };

  int nk = K / BK;
  stage(0, 0);
  for (int k = 0; k < nk; k++) {
    int cur = k & 1;
    __syncthreads();                       // tile-k DMA done; prev reads done
    if (k + 1 < nk) stage((k + 1) * BK, cur ^ 1);
    const u16* Ab = As + cur * ASZ;
    const u16* Bb = Bs + cur * BSZ;
    short8 af[MT], bfr[NT];
    // fragment-major: row-group R at elems R*32 + lane*8 (lane-sequential)
#pragma unroll
    for (int mi = 0; mi < MT; mi++)
      af[mi] = *(const short8*)&Ab[(wm + mi * 16) * 32 + lane * 8];
#pragma unroll
    for (int ni = 0; ni < NT; ni++)
      bfr[ni] = *(const short8*)&Bb[(wn + ni * 16) * 32 + lane * 8];
#pragma unroll
    for (int mi = 0; mi < MT; mi++)
#pragma unroll
      for (int ni = 0; ni < NT; ni++)
        acc[mi][ni] = __builtin_amdgcn_mfma_f32_16x16x32_bf16(
            af[mi], bfr[ni], acc[mi][ni], 0, 0, 0);
  }

#pragma unroll
  for (int mi = 0; mi < MT; mi++) {
#pragma unroll
    for (int ni = 0; ni < NT; ni++) {
      int col = n0 + wn + ni * 16 + l15;
      float bv = bias[col];
#pragma unroll
      for (int r = 0; r < 4; r++) {
        int row = m0 + wm + mi * 16 + quad * 4 + r;
        float v = acc[mi][ni][r] + bv;
        if (act == 1) v = gelu_f(v);
        if (c_fp32) ((float*)Cv)[(size_t)row * N + col] = v;
        else        ((u16*)Cv)[(size_t)row * N + col] = f2bf(v);
      }
    }
  }
}

// ------------- flash-style MFMA attention on fused qkv [M,2304] --------------
__global__ __launch_bounds__(256) void attn_kernel(u16* __restrict__ qkv) {
  __shared__ __align__(16) u16 Qs[64][72];
  __shared__ __align__(16) u16 Ks[64][72];
  __shared__ __align__(16) u16 Vt[64][72];   // [d][key]
  __shared__ __align__(16) u16 Ps[4][16][72];

  const int LD = 2304;
  int bh = blockIdx.x;  // 0..191
  int b = bh / 12;
  int h = bh - b * 12;
  int q0 = blockIdx.y * 64;
  size_t base = (size_t)b * 512 * LD + (size_t)h * 64;
  const u16* qg = qkv + base;
  const u16* kg = qkv + base + 768;
  const u16* vg = qkv + base + 1536;
  int tid = threadIdx.x;
  int wave = tid >> 6;
  int lane = tid & 63;
  int l15 = lane & 15;
  int quad = lane >> 4;

  int srow = tid >> 2;
  int sd = (tid & 3) * 16;

  {
    const u16* qp = qg + (size_t)(q0 + srow) * LD + sd;
    *(int4*)&Qs[srow][sd]     = *(const int4*)qp;
    *(int4*)&Qs[srow][sd + 8] = *(const int4*)(qp + 8);
  }
  __syncthreads();

  short8 aQ[2];
#pragma unroll
  for (int k = 0; k < 2; k++)
    aQ[k] = *(const short8*)&Qs[16 * wave + l15][k * 32 + quad * 8];

  floatx4 O[4];
  float m_r[4], l_r[4];
#pragma unroll
  for (int nt = 0; nt < 4; nt++) O[nt] = (floatx4){0.f, 0.f, 0.f, 0.f};
#pragma unroll
  for (int r = 0; r < 4; r++) { m_r[r] = -1e30f; l_r[r] = 0.f; }

  const float cst = 0.18033688011112042f;  // (1/8) * log2(e)

  for (int c = 0; c < 8; c++) {
    const u16* kp = kg + (size_t)(c * 64 + srow) * LD + sd;
    const u16* vp = vg + (size_t)(c * 64 + srow) * LD + sd;
    int4 kv0 = *(const int4*)kp;
    int4 kv1 = *(const int4*)(kp + 8);
    int4 vv0 = *(const int4*)vp;
    int4 vv1 = *(const int4*)(vp + 8);
    __syncthreads();
    *(int4*)&Ks[srow][sd]     = kv0;
    *(int4*)&Ks[srow][sd + 8] = kv1;
    {
      u16 tv[16];
      *(int4*)tv = vv0;
      *(int4*)(tv + 8) = vv1;
#pragma unroll
      for (int j = 0; j < 16; j++) Vt[sd + j][srow] = tv[j];
    }
    __syncthreads();

    floatx4 S[4];
#pragma unroll
    for (int nt = 0; nt < 4; nt++) {
      floatx4 s = {0.f, 0.f, 0.f, 0.f};
      short8 bK0 = *(const short8*)&Ks[nt * 16 + l15][quad * 8];
      short8 bK1 = *(const short8*)&Ks[nt * 16 + l15][32 + quad * 8];
      s = __builtin_amdgcn_mfma_f32_16x16x32_bf16(aQ[0], bK0, s, 0, 0, 0);
      s = __builtin_amdgcn_mfma_f32_16x16x32_bf16(aQ[1], bK1, s, 0, 0, 0);
      S[nt] = s;
    }

#pragma unroll
    for (int r = 0; r < 4; r++) {
      float s0 = S[0][r] * cst, s1 = S[1][r] * cst;
      float s2 = S[2][r] * cst, s3 = S[3][r] * cst;
      float mr = fmaxf(fmaxf(s0, s1), fmaxf(s2, s3));
#pragma unroll
      for (int off = 1; off < 16; off <<= 1) mr = fmaxf(mr, __shfl_xor(mr, off, 16));
      float m_new = fmaxf(m_r[r], mr);
      float alpha = exp2f(m_r[r] - m_new);
      m_r[r] = m_new;
      float p0 = exp2f(s0 - m_new), p1 = exp2f(s1 - m_new);
      float p2 = exp2f(s2 - m_new), p3 = exp2f(s3 - m_new);
      S[0][r] = p0; S[1][r] = p1; S[2][r] = p2; S[3][r] = p3;
      float sum = p0 + p1 + p2 + p3;
#pragma unroll
      for (int off = 1; off < 16; off <<= 1) sum += __shfl_xor(sum, off, 16);
      l_r[r] = l_r[r] * alpha + sum;
      O[0][r] *= alpha; O[1][r] *= alpha; O[2][r] *= alpha; O[3][r] *= alpha;
    }

#pragma unroll
    for (int nt = 0; nt < 4; nt++)
#pragma unroll
      for (int r = 0; r < 4; r++)
        Ps[wave][quad * 4 + r][nt * 16 + l15] = f2bf(S[nt][r]);

    short8 aP[2];
#pragma unroll
    for (int k = 0; k < 2; k++)
      aP[k] = *(const short8*)&Ps[wave][l15][k * 32 + quad * 8];

#pragma unroll
    for (int nt = 0; nt < 4; nt++) {
      short8 bV0 = *(const short8*)&Vt[nt * 16 + l15][quad * 8];
      short8 bV1 = *(const short8*)&Vt[nt * 16 + l15][32 + quad * 8];
      O[nt] = __builtin_amdgcn_mfma_f32_16x16x32_bf16(aP[0], bV0, O[nt], 0, 0, 0);
      O[nt] = __builtin_amdgcn_mfma_f32_16x16x32_bf16(aP[1], bV1, O[nt], 0, 0, 0);
    }
  }

#pragma unroll
  for (int r = 0; r < 4; r++) {
    float inv = 1.0f / l_r[r];
    int row = q0 + 16 * wave + quad * 4 + r;
    u16* cp = qkv + base + (size_t)row * LD;
#pragma unroll
    for (int nt = 0; nt < 4; nt++)
      cp[nt * 16 + l15] = f2bf(O[nt][r] * inv);
  }
}

// ------------- LN1: out_bf16 = LN(a_bf16 + r_f32) ----------------------------
__global__ __launch_bounds__(256) void ln1_kernel(
    const u16* __restrict__ a, const float* __restrict__ r,
    const float* __restrict__ g, const float* __restrict__ bb,
    u16* __restrict__ out) {
  int row = blockIdx.x;
  int tid = threadIdx.x;
  __shared__ float red[4];
  const u16* ap = a + (size_t)row * 768;
  const float* rp = r + (size_t)row * 768;
  float x0 = bits2f(ap[tid]) + rp[tid];
  float x1 = bits2f(ap[tid + 256]) + rp[tid + 256];
  float x2 = bits2f(ap[tid + 512]) + rp[tid + 512];
  float s = x0 + x1 + x2;
#pragma unroll
  for (int off = 32; off > 0; off >>= 1) s += __shfl_xor(s, off, 64);
  if ((tid & 63) == 0) red[tid >> 6] = s;
  __syncthreads();
  float mu = (red[0] + red[1] + red[2] + red[3]) * (1.0f / 768.0f);
  float d0 = x0 - mu, d1 = x1 - mu, d2 = x2 - mu;
  float vs = d0 * d0 + d1 * d1 + d2 * d2;
#pragma unroll
  for (int off = 32; off > 0; off >>= 1) vs += __shfl_xor(vs, off, 64);
  __syncthreads();
  if ((tid & 63) == 0) red[tid >> 6] = vs;
  __syncthreads();
  float var = (red[0] + red[1] + red[2] + red[3]) * (1.0f / 768.0f);
  float rstd = rsqrtf(var + 1e-12f);
  size_t o = (size_t)row * 768;
  out[o + tid]       = f2bf(d0 * rstd * g[tid] + bb[tid]);
  out[o + tid + 256] = f2bf(d1 * rstd * g[tid + 256] + bb[tid + 256]);
  out[o + tid + 512] = f2bf(d2 * rstd * g[tid + 512] + bb[tid + 512]);
}

// ------------- LN2: out_f32 = LN(a_f32 + r_bf16), in-place safe --------------
__global__ __launch_bounds__(256) void ln2_kernel(
    const float* __restrict__ a, const u16* __restrict__ r,
    const float* __restrict__ g, const float* __restrict__ bb,
    float* __restrict__ out) {
  int row = blockIdx.x;
  int tid = threadIdx.x;
  __shared__ float red[4];
  const float* ap = a + (size_t)row * 768;
  const u16* rp = r + (size_t)row * 768;
  float x0 = ap[tid] + bits2f(rp[tid]);
  float x1 = ap[tid + 256] + bits2f(rp[tid + 256]);
  float x2 = ap[tid + 512] + bits2f(rp[tid + 512]);
  float s = x0 + x1 + x2;
#pragma unroll
  for (int off = 32; off > 0; off >>= 1) s += __shfl_xor(s, off, 64);
  if ((tid & 63) == 0) red[tid >> 6] = s;
  __syncthreads();
  float mu = (red[0] + red[1] + red[2] + red[3]) * (1.0f / 768.0f);
  float d0 = x0 - mu, d1 = x1 - mu, d2 = x2 - mu;
  float vs = d0 * d0 + d1 * d1 + d2 * d2;
#pragma unroll
  for (int off = 32; off > 0; off >>= 1) vs += __shfl_xor(vs, off, 64);
  __syncthreads();
  if ((tid & 63) == 0) red[tid >> 6] = vs;
  __syncthreads();
  float var = (red[0] + red[1] + red[2] + red[3]) * (1.0f / 768.0f);
  float rstd = rsqrtf(var + 1e-12f);
  size_t o = (size_t)row * 768;
  out[o + tid]       = d0 * rstd * g[tid] + bb[tid];
  out[o + tid + 256] = d1 * rstd * g[tid + 256] + bb[tid + 256];
  out[o + tid + 512] = d2 * rstd * g[tid + 512] + bb[tid + 512];
}

extern "C" void kernel_launch(void* const* d_in, const int* in_sizes, int n_in,
                              void* d_out, int out_size, void* d_ws, size_t ws_size,
                              hipStream_t stream) {
  (void)in_sizes; (void)n_in; (void)out_size; (void)ws_size;
  const float* x    = (const float*)d_in[0];
  const float* Wq   = (const float*)d_in[1];
  const float* bq   = (const float*)d_in[2];
  const float* Wk   = (const float*)d_in[3];
  const float* bk   = (const float*)d_in[4];
  const float* Wv   = (const float*)d_in[5];
  const float* bv   = (const float*)d_in[6];
  const float* Wo   = (const float*)d_in[7];
  const float* bo   = (const float*)d_in[8];
  const float* ln1g = (const float*)d_in[9];
  const float* ln1b = (const float*)d_in[10];
  const float* W1   = (const float*)d_in[11];
  const float* b1   = (const float*)d_in[12];
  const float* W2   = (const float*)d_in[13];
  const float* b2   = (const float*)d_in[14];
  const float* ln2g = (const float*)d_in[15];
  const float* ln2b = (const float*)d_in[16];

  const int M = 16 * 512, H = 768, FF = 3072;
  const size_t MH = (size_t)M * H;
  const size_t HH = (size_t)H * H;

  u16* ws    = (u16*)d_ws;
  u16* qkv   = ws;
  u16* xb    = ws + 3 * MH;
  u16* aob   = xb;             // aob overwrites xb (dead after QKV GEMM)
  u16* ffn1  = ws;             // [0,4MH): qkv+aob both dead by FFN1
  u16* hb    = ws + 4 * MH;
  u16* WTqkv = ws + 5 * MH;
  u16* WTo   = WTqkv + 3 * HH;
  u16* WT1   = WTqkv + 4 * HH;
  u16* WT2   = WTqkv;          // 4HH, reused after QKV GEMM
  float* biasqkv = (float*)(WT1 + 4 * HH);
  float* outf = (float*)d_out;

  dim3 tb(256);
  prep_kernel<<<dim3(7689), tb, 0, stream>>>(x, xb, bq, bk, bv, biasqkv,
                                             Wq, Wk, Wv, Wo, W1,
                                             WTqkv, WTo, WT1);

  // fused QKV: [M,2304] = xb[M,768] @ WTqkv^T
  gemm_m97<128><<<dim3(2304 / 128, M / 128), tb, 0, stream>>>(
      xb, H, WTqkv, biasqkv, qkv, M, 2304, H, 0, 0);

  attn_kernel<<<dim3(192, 8), tb, 0, stream>>>(qkv);

  // attn out: aob[M,768] = ctx(q-slot of qkv, lda=2304) @ WTo^T
  gemm_m97<64><<<dim3(H / 64, M / 128), tb, 0, stream>>>(
      qkv, 2304, WTo, bo, aob, M, H, H, 0, 0);
  ln1_kernel<<<dim3(M), tb, 0, stream>>>(aob, x, ln1g, ln1b, hb);

  transpose_k<<<dim3(H / 32, FF / 32), tb, 0, stream>>>(W2, WT2, FF, H);

  gemm_m97<128><<<dim3(FF / 128, M / 128), tb, 0, stream>>>(
      hb, H, WT1, b1, ffn1, M, FF, H, 1, 0);
  gemm_m97<64><<<dim3(H / 64, M / 128), tb, 0, stream>>>(
      ffn1, FF, WT2, b2, outf, M, H, FF, 0, 1);
  ln2_kernel<<<dim3(M), tb, 0, stream>>>(outf, hb, ln2g, ln2b, outf);
}